// Round 14
// baseline (90.933 us; speedup 1.0000x reference)
//
#include <hip/hip_runtime.h>

// MeanTopKPooling2D: x [16,112,112,128] f32 -> out [16,110,110,128] f32
// out[pos,c] = mean(top4 over q of x[b, pix(q,base), c]); pos = b*12100+base;
//   w=v+4q (base=9u+v); t=q*1344+u+w/9; p=w%9; pix=t+2*(t/110)+112*(p/3)+p%3
//
// R14 = R13 + NONTEMPORAL LOADS. Every 128B line is consumed exactly once,
// in full, by one instruction (R10 layout) -> L1 allocation is pure overhead.
// nt loads skip L1 allocate and stream L2->regs. Single-variable A/B vs
// R13's 43.36us; if +-3%, the gather roofline at ~43us is declared.

typedef float f32x4 __attribute__((ext_vector_type(4)));

#define NPOS 12100u
#define NWG  12100           // 193600 pos * 16 thr / 256
#define IMG_BYTES (12544u * 512u)

__global__ __launch_bounds__(256) void meantopk_kernel(const float* __restrict__ x,
                                                       float* __restrict__ out) {
    __shared__ unsigned lds_off[16][9];

    // bijective XCD swizzle: 12100 = 8*1512 + 4
    const unsigned NX = 8u;
    unsigned bid = blockIdx.x;
    const unsigned qq = NWG / NX;        // 1512
    const unsigned rr = NWG % NX;        // 4
    unsigned xcd = bid % NX;
    unsigned idx = bid / NX;
    unsigned wg = (xcd < rr ? xcd * (qq + 1u)
                            : rr * (qq + 1u) + (xcd - rr) * qq) + idx;

    // ---- phase 1: 144 threads compute one (pos-local, q) offset each ----
    unsigned tx = threadIdx.x;
    if (tx < 144u) {
        unsigned lp = tx / 9u;
        unsigned q  = tx - lp * 9u;
        unsigned pos = wg * 16u + lp;
        unsigned base = pos % NPOS;
        unsigned b    = pos / NPOS;
        unsigned u = base / 9u;
        unsigned v = base - u * 9u;
        unsigned w = v + 4u * q;
        unsigned c1 = w / 9u;
        unsigned t  = q * 1344u + u + c1;
        unsigned p  = w - c1 * 9u;
        unsigned p3 = p / 3u;
        unsigned pix = t + 2u * (t / 110u) + 112u * p3 + (p - p3 * 3u);
        lds_off[lp][q] = b * IMG_BYTES + pix * 512u;
    }
    __syncthreads();

    // ---- phase 2: division-free ----
    unsigned tid = wg * 256u + tx;
    unsigned c16 = tid & 7u;             // 16B slot within a 128B line
    unsigned h   = (tid >> 3) & 1u;      // line pair (channels 0-63 / 64-127)
    unsigned lp  = tx >> 4;              // pos-local within block
    unsigned pos = tid >> 4;

    unsigned off[9];
#pragma unroll
    for (int q = 0; q < 9; ++q) off[q] = lds_off[lp][q];

    unsigned slot = c16 * 16u + h * 256u;
    const char* xb = reinterpret_cast<const char*>(x) + slot;
    char*       ob = reinterpret_cast<char*>(out) + (size_t)pos * 512u + slot;

    f32x4 va[9][2];
#pragma unroll
    for (int q = 0; q < 9; ++q) {
        const char* a = xb + off[q];
        va[q][0] = __builtin_nontemporal_load(reinterpret_cast<const f32x4*>(a));
        va[q][1] = __builtin_nontemporal_load(reinterpret_cast<const f32x4*>(a + 128u));
    }
    // keep the 18-load cluster issued before any consumer
    __builtin_amdgcn_sched_barrier(0);

    f32x4 r[2];
#pragma unroll
    for (int j = 0; j < 2; ++j) {
#pragma unroll
        for (int e = 0; e < 4; ++e) {
            float a0 = va[0][j][e], a1 = va[1][j][e], a2 = va[2][j][e], a3 = va[3][j][e];
            float b0 = va[4][j][e], b1 = va[5][j][e], b2 = va[6][j][e], b3 = va[7][j][e];
            float v8 = va[8][j][e];
            // sort4 desc via sort3(max3/min3/med3) + med3 insertion
            float xa = fmaxf(fmaxf(a0, a1), a2);
            float za = fminf(fminf(a0, a1), a2);
            float ya = __builtin_amdgcn_fmed3f(a0, a1, a2);
            float s0 = fmaxf(xa, a3);
            float s1 = __builtin_amdgcn_fmed3f(xa, a3, ya);
            float s2 = __builtin_amdgcn_fmed3f(ya, a3, za);
            float s3 = fminf(za, a3);
            float xb2 = fmaxf(fmaxf(b0, b1), b2);
            float zb = fminf(fminf(b0, b1), b2);
            float yb = __builtin_amdgcn_fmed3f(b0, b1, b2);
            float t0 = fmaxf(xb2, b3);
            float t1 = __builtin_amdgcn_fmed3f(xb2, b3, yb);
            float t2 = __builtin_amdgcn_fmed3f(yb, b3, zb);
            float t3 = fminf(zb, b3);
            // bitonic half-cleaner: top-4 multiset of 8
            float m0 = fmaxf(s0, t3);
            float m1 = fmaxf(s1, t2);
            float m2 = fmaxf(s2, t1);
            float m3 = fmaxf(s3, t0);
            // top4 of {m0..m3, v8} = sum5 - min5
            float sum = (m0 + m1) + (m2 + m3) + v8;
            float mn  = fminf(fminf(fminf(m0, m1), fminf(m2, m3)), v8);
            r[j][e] = (sum - mn) * 0.25f;
        }
    }
    *reinterpret_cast<f32x4*>(ob)         = r[0];
    *reinterpret_cast<f32x4*>(ob + 128u)  = r[1];
}

extern "C" void kernel_launch(void* const* d_in, const int* in_sizes, int n_in,
                              void* d_out, int out_size, void* d_ws, size_t ws_size,
                              hipStream_t stream) {
    const float* x = (const float*)d_in[0];
    float* out = (float*)d_out;
    meantopk_kernel<<<NWG, 256, 0, stream>>>(x, out);
}

// Round 15
// 43.167 us; speedup vs baseline: 2.1065x; 2.1065x over previous
//
#include <hip/hip_runtime.h>

// MeanTopKPooling2D: x [16,112,112,128] f32 -> out [16,110,110,128] f32
// out[pos,c] = mean(top4 over q of x[b, pix(q,base), c]); pos = b*12100+base;
//   w=v+4q (base=9u+v); t=q*1344+u+w/9; p=w%9; pix=t+2*(t/110)+112*(p/3)+p%3
//
// FINAL (= R13, 43.36us): full-line layout (thread = (pos,c16,h): 16B slot of
// a 128B line; 8 lanes x 16B = one fully-consumed line per load; 18
// loads/thread) + LDS address precompute (16 pos/block, division-free phase
// 2) + bijective XCD swizzle + plain stores.
// Ruled out by A/B: NT stores (0%), NT loads (-110%: breaks L3 reuse), 2x TLP
// (-2%), -30% VALU (-2.5%), MLP forcing (R5-R9 all <=0). Remaining wall:
// 892MB irreducible L2->CU gather traffic + 99MB HBM write drain, both pipes
// concurrently near practical ceilings.

typedef float f32x4 __attribute__((ext_vector_type(4)));

#define NPOS 12100u
#define NWG  12100           // 193600 pos * 16 thr / 256
#define IMG_BYTES (12544u * 512u)

__global__ __launch_bounds__(256) void meantopk_kernel(const float* __restrict__ x,
                                                       float* __restrict__ out) {
    __shared__ unsigned lds_off[16][9];

    // bijective XCD swizzle: 12100 = 8*1512 + 4
    const unsigned NX = 8u;
    unsigned bid = blockIdx.x;
    const unsigned qq = NWG / NX;        // 1512
    const unsigned rr = NWG % NX;        // 4
    unsigned xcd = bid % NX;
    unsigned idx = bid / NX;
    unsigned wg = (xcd < rr ? xcd * (qq + 1u)
                            : rr * (qq + 1u) + (xcd - rr) * qq) + idx;

    // ---- phase 1: 144 threads compute one (pos-local, q) offset each ----
    unsigned tx = threadIdx.x;
    if (tx < 144u) {
        unsigned lp = tx / 9u;
        unsigned q  = tx - lp * 9u;
        unsigned pos = wg * 16u + lp;
        unsigned base = pos % NPOS;
        unsigned b    = pos / NPOS;
        unsigned u = base / 9u;
        unsigned v = base - u * 9u;
        unsigned w = v + 4u * q;
        unsigned c1 = w / 9u;
        unsigned t  = q * 1344u + u + c1;
        unsigned p  = w - c1 * 9u;
        unsigned p3 = p / 3u;
        unsigned pix = t + 2u * (t / 110u) + 112u * p3 + (p - p3 * 3u);
        lds_off[lp][q] = b * IMG_BYTES + pix * 512u;
    }
    __syncthreads();

    // ---- phase 2: division-free ----
    unsigned tid = wg * 256u + tx;
    unsigned c16 = tid & 7u;             // 16B slot within a 128B line
    unsigned h   = (tid >> 3) & 1u;      // line pair (channels 0-63 / 64-127)
    unsigned lp  = tx >> 4;              // pos-local within block
    unsigned pos = tid >> 4;

    unsigned off[9];
#pragma unroll
    for (int q = 0; q < 9; ++q) off[q] = lds_off[lp][q];

    unsigned slot = c16 * 16u + h * 256u;
    const char* xb = reinterpret_cast<const char*>(x) + slot;
    char*       ob = reinterpret_cast<char*>(out) + (size_t)pos * 512u + slot;

    f32x4 va[9][2];
#pragma unroll
    for (int q = 0; q < 9; ++q) {
        const char* a = xb + off[q];
        va[q][0] = *reinterpret_cast<const f32x4*>(a);          // line 2h
        va[q][1] = *reinterpret_cast<const f32x4*>(a + 128u);   // line 2h+1
    }
    // keep the 18-load cluster issued before any consumer
    __builtin_amdgcn_sched_barrier(0);

    f32x4 r[2];
#pragma unroll
    for (int j = 0; j < 2; ++j) {
#pragma unroll
        for (int e = 0; e < 4; ++e) {
            float a0 = va[0][j][e], a1 = va[1][j][e], a2 = va[2][j][e], a3 = va[3][j][e];
            float b0 = va[4][j][e], b1 = va[5][j][e], b2 = va[6][j][e], b3 = va[7][j][e];
            float v8 = va[8][j][e];
            // sort4 desc via sort3(max3/min3/med3) + med3 insertion
            float xa = fmaxf(fmaxf(a0, a1), a2);
            float za = fminf(fminf(a0, a1), a2);
            float ya = __builtin_amdgcn_fmed3f(a0, a1, a2);
            float s0 = fmaxf(xa, a3);
            float s1 = __builtin_amdgcn_fmed3f(xa, a3, ya);
            float s2 = __builtin_amdgcn_fmed3f(ya, a3, za);
            float s3 = fminf(za, a3);
            float xb2 = fmaxf(fmaxf(b0, b1), b2);
            float zb = fminf(fminf(b0, b1), b2);
            float yb = __builtin_amdgcn_fmed3f(b0, b1, b2);
            float t0 = fmaxf(xb2, b3);
            float t1 = __builtin_amdgcn_fmed3f(xb2, b3, yb);
            float t2 = __builtin_amdgcn_fmed3f(yb, b3, zb);
            float t3 = fminf(zb, b3);
            // bitonic half-cleaner: top-4 multiset of 8
            float m0 = fmaxf(s0, t3);
            float m1 = fmaxf(s1, t2);
            float m2 = fmaxf(s2, t1);
            float m3 = fmaxf(s3, t0);
            // top4 of {m0..m3, v8} = sum5 - min5
            float sum = (m0 + m1) + (m2 + m3) + v8;
            float mn  = fminf(fminf(fminf(m0, m1), fminf(m2, m3)), v8);
            r[j][e] = (sum - mn) * 0.25f;
        }
    }
    *reinterpret_cast<f32x4*>(ob)         = r[0];
    *reinterpret_cast<f32x4*>(ob + 128u)  = r[1];
}

extern "C" void kernel_launch(void* const* d_in, const int* in_sizes, int n_in,
                              void* d_out, int out_size, void* d_ws, size_t ws_size,
                              hipStream_t stream) {
    const float* x = (const float*)d_in[0];
    float* out = (float*)d_out;
    meantopk_kernel<<<NWG, 256, 0, stream>>>(x, out);
}